// Round 1
// baseline (171.167 us; speedup 1.0000x reference)
//
#include <hip/hip_runtime.h>

#define BATCH 1024
#define PP 784          // 28*28

// ============================ TDA kernel ============================
// landscape top-2 == tent at the two smallest v (monotone in v).
// Per sample: reduce (min1,min2,max) over 784, then x_br[j] =
// relu(g_b[j] + sum_i lambda_i * g_w[i*32+j]) computed by 64 lanes.
__global__ __launch_bounds__(256) void tda_kernel(
    const float* __restrict__ dtm1, const float* __restrict__ dtm2,
    const float* __restrict__ g1w, const float* __restrict__ g1b,
    const float* __restrict__ g2w, const float* __restrict__ g2b,
    float* __restrict__ x12)
{
  const int b = blockIdx.x;
  const int tid = threadIdx.x;
  __shared__ float red[2][4][3];   // [branch][wave][m1,m2,mx]
  __shared__ float fin[2][3];

  for (int br = 0; br < 2; ++br) {
    const float* v = (br == 0 ? dtm1 : dtm2) + b * PP;
    float m1 = 1e30f, m2 = 1e30f, mx = -1e30f;
    // 196 float4 loads cover 784 elements
    for (int i = tid; i < 196; i += 256) {
      float4 x4 = *(const float4*)&v[i * 4];
      float xs[4] = {x4.x, x4.y, x4.z, x4.w};
#pragma unroll
      for (int k = 0; k < 4; ++k) {
        float x = xs[k];
        mx = fmaxf(mx, x);
        float nm1 = fminf(m1, x);
        m2 = fminf(m2, fmaxf(m1, x));
        m1 = nm1;
      }
    }
#pragma unroll
    for (int off = 32; off >= 1; off >>= 1) {
      float o1 = __shfl_xor(m1, off);
      float o2 = __shfl_xor(m2, off);
      float ox = __shfl_xor(mx, off);
      mx = fmaxf(mx, ox);
      float nm1 = fminf(m1, o1);
      m2 = fminf(fminf(m2, o2), fmaxf(m1, o1));
      m1 = nm1;
    }
    if ((tid & 63) == 0) {
      int wid = tid >> 6;
      red[br][wid][0] = m1; red[br][wid][1] = m2; red[br][wid][2] = mx;
    }
  }
  __syncthreads();
  if (tid < 2) {
    float m1 = 1e30f, m2 = 1e30f, mx = -1e30f;
#pragma unroll
    for (int w = 0; w < 4; ++w) {
      float o1 = red[tid][w][0], o2 = red[tid][w][1], ox = red[tid][w][2];
      mx = fmaxf(mx, ox);
      float nm1 = fminf(m1, o1);
      m2 = fminf(fminf(m2, o2), fmaxf(m1, o1));
      m1 = nm1;
    }
    fin[tid][0] = m1; fin[tid][1] = m2; fin[tid][2] = mx;
  }
  __syncthreads();
  if (tid < 64) {
    const int br = tid >> 5, j = tid & 31;
    const float m1 = fin[br][0], m2 = fin[br][1], mx = fin[br][2];
    const float* gw = br ? g2w : g1w;
    const float* gb = br ? g2b : g1b;
    const float t0 = br ? 0.05f : 0.01f;
    const float dt = br ? (0.25f / 31.0f) : (0.28f / 31.0f);
    float acc = gb[j];
#pragma unroll 4
    for (int i = 0; i < 64; ++i) {
      const int k = i >> 5, ti = i & 31;
      float tv = t0 + dt * (float)ti;
      float vk = k ? m2 : m1;
      float lam = fmaxf(0.0f, fminf(tv - vk, mx - tv));
      acc = fmaf(lam, gw[i * 32 + j], acc);
    }
    x12[b * 64 + br * 32 + j] = fmaxf(acc, 0.0f);
  }
}

// ============================ CONV kernel ============================
// One half-image (14 output rows) per block; h1 (conv1 output, 32ch) staged
// in LDS as [c][16 rows][32 cols] with a zeroed guard so x=-1 / x=28 /
// out-of-range rows read zeros.  ~70KB LDS -> 2 blocks/CU.
__global__ __launch_bounds__(256) void conv_kernel(
    const float* __restrict__ xin,
    const float* __restrict__ w1g, const float* __restrict__ b1g,
    const float* __restrict__ w2g, const float* __restrict__ b2g,
    float* __restrict__ hf)
{
  __shared__ __align__(16) float tileG[592];          // 4 guard + 18*32 input tile
  __shared__ __align__(16) float h1G[16400];          // 4 guard + 32*16*32
  __shared__ __align__(16) float w1L[384];            // [c][12] (9 taps + pad)
  __shared__ __align__(16) float w2L[384];
  __shared__ float b1L[32];

  const int blk = blockIdx.x;
  const int b = blk >> 1;
  const int r0 = (blk & 1) * 14;        // first output row of this half
  const int tid = threadIdx.x;

  float* tile = tileG + 4;              // rows ty=0..17 <-> global rows r0-2..r0+15
  float* h1   = h1G + 4;                // h1[c*512 + hy*32 + x], hy <-> global row r0-1+hy

  // ---- phase 1: zero LDS, stage weights ----
  float4* tg4 = (float4*)tileG;
  for (int i = tid; i < 148; i += 256) tg4[i] = make_float4(0.f, 0.f, 0.f, 0.f);
  float4* h14 = (float4*)h1G;
  for (int i = tid; i < 4100; i += 256) h14[i] = make_float4(0.f, 0.f, 0.f, 0.f);
  for (int i = tid; i < 288; i += 256) {        // transpose [tap][c] -> [c][12]
    int c = i & 31, tap = i >> 5;
    w1L[c * 12 + tap] = w1g[i];
    w2L[c * 12 + tap] = w2g[i];
  }
  if (tid < 32) b1L[tid] = b1g[tid];
  __syncthreads();

  // ---- phase 2: load input interior (16 valid rows either half) ----
  const int gfirst = (r0 == 0) ? 0 : 12;
  for (int i = tid; i < 112; i += 256) {
    int rr = i / 7, cq = i % 7;
    int gy = gfirst + rr;
    int ty = gy - (r0 - 2);
    *(float4*)&tile[ty * 32 + cq * 4] =
        *(const float4*)&xin[b * PP + gy * 28 + cq * 4];
  }
  __syncthreads();

  // ---- phase 3: conv1 (+bias, relu) into LDS h1 ----
  // valid h1 rows: gy in [max(0,r0-1), min(27,r0+14)] -> 15 rows, 14 pixel-pairs
  const int gy0 = (r0 == 0) ? 0 : (r0 - 1);
  if (tid < 210) {
    int vrow = tid / 14, pair = tid % 14;
    int gy = gy0 + vrow;
    int hy = gy - (r0 - 1);
    int x0 = pair * 2;
    float p[3][4];
#pragma unroll
    for (int dr = 0; dr < 3; ++dr) {
      int base = (hy + dr) * 32 + x0 - 1;      // input row gy-1+dr -> ty = hy+dr
      p[dr][0] = tile[base];     p[dr][1] = tile[base + 1];
      p[dr][2] = tile[base + 2]; p[dr][3] = tile[base + 3];
    }
#pragma unroll 2
    for (int c = 0; c < 32; ++c) {
      float4 wa = *(float4*)&w1L[c * 12];
      float4 wb = *(float4*)&w1L[c * 12 + 4];
      float w8 = w1L[c * 12 + 8];
      float bb = b1L[c];
      float a0 = bb, a1 = bb;
      a0 = fmaf(p[0][0], wa.x, a0); a0 = fmaf(p[0][1], wa.y, a0); a0 = fmaf(p[0][2], wa.z, a0);
      a1 = fmaf(p[0][1], wa.x, a1); a1 = fmaf(p[0][2], wa.y, a1); a1 = fmaf(p[0][3], wa.z, a1);
      a0 = fmaf(p[1][0], wa.w, a0); a0 = fmaf(p[1][1], wb.x, a0); a0 = fmaf(p[1][2], wb.y, a0);
      a1 = fmaf(p[1][1], wa.w, a1); a1 = fmaf(p[1][2], wb.x, a1); a1 = fmaf(p[1][3], wb.y, a1);
      a0 = fmaf(p[2][0], wb.z, a0); a0 = fmaf(p[2][1], wb.w, a0); a0 = fmaf(p[2][2], w8, a0);
      a1 = fmaf(p[2][1], wb.z, a1); a1 = fmaf(p[2][2], wb.w, a1); a1 = fmaf(p[2][3], w8, a1);
      a0 = fmaxf(a0, 0.f); a1 = fmaxf(a1, 0.f);
      *(float2*)&h1[c * 512 + hy * 32 + x0] = make_float2(a0, a1);
    }
  }
  __syncthreads();

  // ---- phase 4: conv2 (+bias, relu) -> hf ----
  const float b2v = b2g[0];
  if (tid < 196) {
    int orow = tid / 14, pair = tid % 14;
    int gy = r0 + orow;
    int x0 = pair * 2;
    float a0 = b2v, a1 = b2v;
#pragma unroll 2
    for (int c = 0; c < 32; ++c) {
      float4 wa = *(float4*)&w2L[c * 12];
      float4 wb = *(float4*)&w2L[c * 12 + 4];
      float w8 = w2L[c * 12 + 8];
      const float* hp = &h1[c * 512 + orow * 32 + x0 - 1];  // row hy=orow+dr
      float q00 = hp[0],  q01 = hp[1],  q02 = hp[2],  q03 = hp[3];
      float q10 = hp[32], q11 = hp[33], q12 = hp[34], q13 = hp[35];
      float q20 = hp[64], q21 = hp[65], q22 = hp[66], q23 = hp[67];
      a0 = fmaf(q00, wa.x, a0); a0 = fmaf(q01, wa.y, a0); a0 = fmaf(q02, wa.z, a0);
      a1 = fmaf(q01, wa.x, a1); a1 = fmaf(q02, wa.y, a1); a1 = fmaf(q03, wa.z, a1);
      a0 = fmaf(q10, wa.w, a0); a0 = fmaf(q11, wb.x, a0); a0 = fmaf(q12, wb.y, a0);
      a1 = fmaf(q11, wa.w, a1); a1 = fmaf(q12, wb.x, a1); a1 = fmaf(q13, wb.y, a1);
      a0 = fmaf(q20, wb.z, a0); a0 = fmaf(q21, wb.w, a0); a0 = fmaf(q22, w8, a0);
      a1 = fmaf(q21, wb.z, a1); a1 = fmaf(q22, wb.w, a1); a1 = fmaf(q23, w8, a1);
    }
    a0 = fmaxf(a0, 0.f); a1 = fmaxf(a1, 0.f);
    *(float2*)&hf[b * PP + gy * 28 + x0] = make_float2(a0, a1);
  }
}

// ============================ FC kernel ============================
// 4 samples/block, 256 blocks.  j = tid&63 output unit, part = tid>>6 owns a
// disjoint 212-wide slice of i (each wave reads distinct weight rows once).
__global__ __launch_bounds__(256) void fc_kernel(
    const float* __restrict__ hf, const float* __restrict__ x12,
    const float* __restrict__ w1, const float* __restrict__ b1,
    const float* __restrict__ w2, const float* __restrict__ b2,
    float* __restrict__ out)
{
  __shared__ __align__(16) float zL[4][864];   // 848 used
  __shared__ float pL[4][4][64];               // [part][s][j]
  __shared__ float z1L[4][64];
  const int blk = blockIdx.x, tid = threadIdx.x;
  const int s0 = blk * 4;

  for (int i = tid; i < 848; i += 256) {       // 212 float4 per sample
    int s = i / 212, q = i % 212;
    if (q < 196)
      *(float4*)&zL[s][q * 4] = *(const float4*)&hf[(s0 + s) * 784 + q * 4];
    else
      *(float4*)&zL[s][784 + (q - 196) * 4] =
          *(const float4*)&x12[(s0 + s) * 64 + (q - 196) * 4];
  }
  __syncthreads();

  const int j = tid & 63, part = tid >> 6;
  float acc0 = 0.f, acc1 = 0.f, acc2 = 0.f, acc3 = 0.f;
  const int i0 = part * 212;
#pragma unroll 2
  for (int i = i0; i < i0 + 212; i += 4) {
    float4 z0 = *(float4*)&zL[0][i];
    float4 z1 = *(float4*)&zL[1][i];
    float4 z2 = *(float4*)&zL[2][i];
    float4 z3 = *(float4*)&zL[3][i];
    float wA = w1[(i + 0) * 64 + j];
    float wB = w1[(i + 1) * 64 + j];
    float wC = w1[(i + 2) * 64 + j];
    float wD = w1[(i + 3) * 64 + j];
    acc0 = fmaf(z0.x, wA, acc0); acc0 = fmaf(z0.y, wB, acc0);
    acc0 = fmaf(z0.z, wC, acc0); acc0 = fmaf(z0.w, wD, acc0);
    acc1 = fmaf(z1.x, wA, acc1); acc1 = fmaf(z1.y, wB, acc1);
    acc1 = fmaf(z1.z, wC, acc1); acc1 = fmaf(z1.w, wD, acc1);
    acc2 = fmaf(z2.x, wA, acc2); acc2 = fmaf(z2.y, wB, acc2);
    acc2 = fmaf(z2.z, wC, acc2); acc2 = fmaf(z2.w, wD, acc2);
    acc3 = fmaf(z3.x, wA, acc3); acc3 = fmaf(z3.y, wB, acc3);
    acc3 = fmaf(z3.z, wC, acc3); acc3 = fmaf(z3.w, wD, acc3);
  }
  pL[part][0][j] = acc0; pL[part][1][j] = acc1;
  pL[part][2][j] = acc2; pL[part][3][j] = acc3;
  __syncthreads();
  {
    int s = tid >> 6, jj = tid & 63;
    float v = pL[0][s][jj] + pL[1][s][jj] + pL[2][s][jj] + pL[3][s][jj] + b1[jj];
    z1L[s][jj] = fmaxf(v, 0.f);
  }
  __syncthreads();
  if (tid < 40) {
    int s = tid / 10, o = tid % 10;
    float acc = b2[o];
#pragma unroll 8
    for (int jj = 0; jj < 64; ++jj)
      acc = fmaf(z1L[s][jj], w2[jj * 10 + o], acc);
    out[(s0 + s) * 10 + o] = acc;
  }
}

extern "C" void kernel_launch(void* const* d_in, const int* in_sizes, int n_in,
                              void* d_out, int out_size, void* d_ws, size_t ws_size,
                              hipStream_t stream) {
  const float* x       = (const float*)d_in[0];
  const float* dtm005  = (const float*)d_in[1];
  const float* dtm02   = (const float*)d_in[2];
  const float* conv_w1 = (const float*)d_in[3];
  const float* conv_b1 = (const float*)d_in[4];
  const float* conv_w2 = (const float*)d_in[5];
  const float* conv_b2 = (const float*)d_in[6];
  const float* g1_w    = (const float*)d_in[7];
  const float* g1_b    = (const float*)d_in[8];
  const float* g2_w    = (const float*)d_in[9];
  const float* g2_b    = (const float*)d_in[10];
  const float* fc1_w   = (const float*)d_in[11];
  const float* fc1_b   = (const float*)d_in[12];
  const float* fc2_w   = (const float*)d_in[13];
  const float* fc2_b   = (const float*)d_in[14];
  float* out = (float*)d_out;

  float* hfW  = (float*)d_ws;            // [1024*784]
  float* x12W = hfW + BATCH * PP;        // [1024*64]

  tda_kernel<<<BATCH, 256, 0, stream>>>(dtm005, dtm02, g1_w, g1_b, g2_w, g2_b, x12W);
  conv_kernel<<<BATCH * 2, 256, 0, stream>>>(x, conv_w1, conv_b1, conv_w2, conv_b2, hfW);
  fc_kernel<<<BATCH / 4, 256, 0, stream>>>(hfW, x12W, fc1_w, fc1_b, fc2_w, fc2_b, out);
}

// Round 2
// 130.121 us; speedup vs baseline: 1.3154x; 1.3154x over previous
//
#include <hip/hip_runtime.h>

#define BATCH 1024
#define PP 784          // 28*28

// ================= fused CONV (blocks 0..1023) + TDA (blocks 1024..2047) =================
// CONV: one image per block, 4 waves. Wave w owns channels [8w,8w+8).
// lane = x (0..31, 28 valid) + 32*sub; per channel-pair cp, lane's channel
// c = 8w + 2cp + sub. Rolling 3-row input window in registers; h1 row computed
// in-register, x-neighbors via intra-32 shuffles, conv2 contributions scattered
// into static acc[28] (y fully unrolled). No h1 LDS array at all.
__global__ __launch_bounds__(256) void convtda_kernel(
    const float* __restrict__ xin,
    const float* __restrict__ w1g, const float* __restrict__ b1g,
    const float* __restrict__ w2g, const float* __restrict__ b2g,
    const float* __restrict__ dtm1, const float* __restrict__ dtm2,
    const float* __restrict__ g1w, const float* __restrict__ g1b,
    const float* __restrict__ g2w, const float* __restrict__ g2b,
    float* __restrict__ hf, float* __restrict__ x12)
{
  const int tid = threadIdx.x;

  if (blockIdx.x >= BATCH) {
    // ============================ TDA branch ============================
    const int b = blockIdx.x - BATCH;
    __shared__ float red[2][4][3];
    __shared__ float fin[2][3];

    for (int br = 0; br < 2; ++br) {
      const float* v = (br == 0 ? dtm1 : dtm2) + b * PP;
      float m1 = 1e30f, m2 = 1e30f, mx = -1e30f;
      for (int i = tid; i < 196; i += 256) {
        float4 x4 = *(const float4*)&v[i * 4];
        float xs[4] = {x4.x, x4.y, x4.z, x4.w};
#pragma unroll
        for (int k = 0; k < 4; ++k) {
          float x = xs[k];
          mx = fmaxf(mx, x);
          float nm1 = fminf(m1, x);
          m2 = fminf(m2, fmaxf(m1, x));
          m1 = nm1;
        }
      }
#pragma unroll
      for (int off = 32; off >= 1; off >>= 1) {
        float o1 = __shfl_xor(m1, off);
        float o2 = __shfl_xor(m2, off);
        float ox = __shfl_xor(mx, off);
        mx = fmaxf(mx, ox);
        float nm1 = fminf(m1, o1);
        m2 = fminf(fminf(m2, o2), fmaxf(m1, o1));
        m1 = nm1;
      }
      if ((tid & 63) == 0) {
        int wid = tid >> 6;
        red[br][wid][0] = m1; red[br][wid][1] = m2; red[br][wid][2] = mx;
      }
    }
    __syncthreads();
    if (tid < 2) {
      float m1 = 1e30f, m2 = 1e30f, mx = -1e30f;
#pragma unroll
      for (int w = 0; w < 4; ++w) {
        float o1 = red[tid][w][0], o2 = red[tid][w][1], ox = red[tid][w][2];
        mx = fmaxf(mx, ox);
        float nm1 = fminf(m1, o1);
        m2 = fminf(fminf(m2, o2), fmaxf(m1, o1));
        m1 = nm1;
      }
      fin[tid][0] = m1; fin[tid][1] = m2; fin[tid][2] = mx;
    }
    __syncthreads();
    if (tid < 64) {
      const int br = tid >> 5, j = tid & 31;
      const float m1 = fin[br][0], m2 = fin[br][1], mx = fin[br][2];
      const float* gw = br ? g2w : g1w;
      const float* gb = br ? g2b : g1b;
      const float t0 = br ? 0.05f : 0.01f;
      const float dt = br ? (0.25f / 31.0f) : (0.28f / 31.0f);
      float acc = gb[j];
#pragma unroll 4
      for (int i = 0; i < 64; ++i) {
        const int k = i >> 5, ti = i & 31;
        float tv = t0 + dt * (float)ti;
        float vk = k ? m2 : m1;
        float lam = fmaxf(0.0f, fminf(tv - vk, mx - tv));
        acc = fmaf(lam, gw[i * 32 + j], acc);
      }
      x12[b * 64 + br * 32 + j] = fmaxf(acc, 0.0f);
    }
    return;
  }

  // ============================ CONV branch ============================
  const int b = blockIdx.x;
  const int lane = tid & 63;
  const int w = tid >> 6;          // wave id 0..3
  const int x = lane & 31;         // x position (28 valid)
  const int sub = lane >> 5;       // sub-channel 0/1

  __shared__ float inL[28][36];    // col0 & cols29..35 zero; col x+1 = image x
  __shared__ float w1L[9][32];     // [tap][c]
  __shared__ float w2L[9][32];
  __shared__ float b1L[32];
  __shared__ float pL[4][28][28];  // per-wave partial conv2 sums

  // stage: pads + interior (disjoint writes -> one barrier)
  for (int i = tid; i < 224; i += 256) {
    int y = i >> 3, k = i & 7;
    inL[y][k == 0 ? 0 : 28 + k] = 0.f;
  }
  for (int i = tid; i < 784; i += 256)
    inL[i / 28][i % 28 + 1] = xin[b * PP + i];
  for (int i = tid; i < 288; i += 256) {
    ((float*)w1L)[i] = w1g[i];
    ((float*)w2L)[i] = w2g[i];
  }
  if (tid < 32) b1L[tid] = b1g[tid];
  __syncthreads();

  float acc[28];
#pragma unroll
  for (int y = 0; y < 28; ++y) acc[y] = 0.f;

#pragma unroll 1
  for (int cp = 0; cp < 4; ++cp) {
    const int c = (w << 3) + (cp << 1) + sub;
    float wa[9], wb[9];
#pragma unroll
    for (int t = 0; t < 9; ++t) { wa[t] = w1L[t][c]; wb[t] = w2L[t][c]; }
    const float bb = b1L[c];

    float ra0 = 0.f, ra1 = 0.f, ra2 = 0.f;               // row y-1
    float rb0 = inL[0][x], rb1 = inL[0][x + 1], rb2 = inL[0][x + 2];  // row y

#pragma unroll
    for (int y = 0; y < 28; ++y) {
      float rc0, rc1, rc2;                               // row y+1
      if (y + 1 < 28) {
        rc0 = inL[y + 1][x]; rc1 = inL[y + 1][x + 1]; rc2 = inL[y + 1][x + 2];
      } else {
        rc0 = 0.f; rc1 = 0.f; rc2 = 0.f;
      }
      float h = bb;
      h = fmaf(ra0, wa[0], h); h = fmaf(ra1, wa[1], h); h = fmaf(ra2, wa[2], h);
      h = fmaf(rb0, wa[3], h); h = fmaf(rb1, wa[4], h); h = fmaf(rb2, wa[5], h);
      h = fmaf(rc0, wa[6], h); h = fmaf(rc1, wa[7], h); h = fmaf(rc2, wa[8], h);
      h = (x < 28) ? fmaxf(h, 0.f) : 0.f;                // h1[y][x][c]; x>=28 -> 0
      float hl = __shfl_up(h, 1, 32);  hl = (x == 0) ? 0.f : hl;   // h1[x-1]
      float hr = __shfl_down(h, 1, 32);                             // h1[x+1] (x=27 gets lane28=0)
      // h1 row y contributes to out rows y+1 (w2 row 0), y (row 1), y-1 (row 2)
      if (y + 1 < 28) {
        acc[y + 1] = fmaf(hl, wb[0], acc[y + 1]);
        acc[y + 1] = fmaf(h , wb[1], acc[y + 1]);
        acc[y + 1] = fmaf(hr, wb[2], acc[y + 1]);
      }
      acc[y] = fmaf(hl, wb[3], acc[y]);
      acc[y] = fmaf(h , wb[4], acc[y]);
      acc[y] = fmaf(hr, wb[5], acc[y]);
      if (y > 0) {
        acc[y - 1] = fmaf(hl, wb[6], acc[y - 1]);
        acc[y - 1] = fmaf(h , wb[7], acc[y - 1]);
        acc[y - 1] = fmaf(hr, wb[8], acc[y - 1]);
      }
      ra0 = rb0; ra1 = rb1; ra2 = rb2;
      rb0 = rc0; rb1 = rc1; rb2 = rc2;
    }
  }

  // reduce sub-channel halves (partner lane = lane^32, same x)
#pragma unroll
  for (int y = 0; y < 28; ++y) acc[y] += __shfl_xor(acc[y], 32);
  if (sub == 0 && x < 28) {
#pragma unroll
    for (int y = 0; y < 28; ++y) pL[w][y][x] = acc[y];
  }
  __syncthreads();

  const float b2v = b2g[0];
  const float* pw = (const float*)pL;
  for (int u = tid; u < 784; u += 256) {
    float v = pw[u] + pw[784 + u] + pw[1568 + u] + pw[2352 + u] + b2v;
    hf[b * PP + u] = fmaxf(v, 0.f);
  }
}

// ============================ FC kernel ============================
__global__ __launch_bounds__(256) void fc_kernel(
    const float* __restrict__ hf, const float* __restrict__ x12,
    const float* __restrict__ w1, const float* __restrict__ b1,
    const float* __restrict__ w2, const float* __restrict__ b2,
    float* __restrict__ out)
{
  __shared__ __align__(16) float zL[4][864];   // 848 used
  __shared__ float pL[4][4][64];               // [part][s][j]
  __shared__ float z1L[4][64];
  const int blk = blockIdx.x, tid = threadIdx.x;
  const int s0 = blk * 4;

  for (int i = tid; i < 848; i += 256) {       // 212 float4 per sample
    int s = i / 212, q = i % 212;
    if (q < 196)
      *(float4*)&zL[s][q * 4] = *(const float4*)&hf[(s0 + s) * 784 + q * 4];
    else
      *(float4*)&zL[s][784 + (q - 196) * 4] =
          *(const float4*)&x12[(s0 + s) * 64 + (q - 196) * 4];
  }
  __syncthreads();

  const int j = tid & 63, part = tid >> 6;
  float acc0 = 0.f, acc1 = 0.f, acc2 = 0.f, acc3 = 0.f;
  const int i0 = part * 212;
#pragma unroll 2
  for (int i = i0; i < i0 + 212; i += 4) {
    float4 z0 = *(float4*)&zL[0][i];
    float4 z1 = *(float4*)&zL[1][i];
    float4 z2 = *(float4*)&zL[2][i];
    float4 z3 = *(float4*)&zL[3][i];
    float wA = w1[(i + 0) * 64 + j];
    float wB = w1[(i + 1) * 64 + j];
    float wC = w1[(i + 2) * 64 + j];
    float wD = w1[(i + 3) * 64 + j];
    acc0 = fmaf(z0.x, wA, acc0); acc0 = fmaf(z0.y, wB, acc0);
    acc0 = fmaf(z0.z, wC, acc0); acc0 = fmaf(z0.w, wD, acc0);
    acc1 = fmaf(z1.x, wA, acc1); acc1 = fmaf(z1.y, wB, acc1);
    acc1 = fmaf(z1.z, wC, acc1); acc1 = fmaf(z1.w, wD, acc1);
    acc2 = fmaf(z2.x, wA, acc2); acc2 = fmaf(z2.y, wB, acc2);
    acc2 = fmaf(z2.z, wC, acc2); acc2 = fmaf(z2.w, wD, acc2);
    acc3 = fmaf(z3.x, wA, acc3); acc3 = fmaf(z3.y, wB, acc3);
    acc3 = fmaf(z3.z, wC, acc3); acc3 = fmaf(z3.w, wD, acc3);
  }
  pL[part][0][j] = acc0; pL[part][1][j] = acc1;
  pL[part][2][j] = acc2; pL[part][3][j] = acc3;
  __syncthreads();
  {
    int s = tid >> 6, jj = tid & 63;
    float v = pL[0][s][jj] + pL[1][s][jj] + pL[2][s][jj] + pL[3][s][jj] + b1[jj];
    z1L[s][jj] = fmaxf(v, 0.f);
  }
  __syncthreads();
  if (tid < 40) {
    int s = tid / 10, o = tid % 10;
    float acc = b2[o];
#pragma unroll 8
    for (int jj = 0; jj < 64; ++jj)
      acc = fmaf(z1L[s][jj], w2[jj * 10 + o], acc);
    out[(s0 + s) * 10 + o] = acc;
  }
}

extern "C" void kernel_launch(void* const* d_in, const int* in_sizes, int n_in,
                              void* d_out, int out_size, void* d_ws, size_t ws_size,
                              hipStream_t stream) {
  const float* x       = (const float*)d_in[0];
  const float* dtm005  = (const float*)d_in[1];
  const float* dtm02   = (const float*)d_in[2];
  const float* conv_w1 = (const float*)d_in[3];
  const float* conv_b1 = (const float*)d_in[4];
  const float* conv_w2 = (const float*)d_in[5];
  const float* conv_b2 = (const float*)d_in[6];
  const float* g1_w    = (const float*)d_in[7];
  const float* g1_b    = (const float*)d_in[8];
  const float* g2_w    = (const float*)d_in[9];
  const float* g2_b    = (const float*)d_in[10];
  const float* fc1_w   = (const float*)d_in[11];
  const float* fc1_b   = (const float*)d_in[12];
  const float* fc2_w   = (const float*)d_in[13];
  const float* fc2_b   = (const float*)d_in[14];
  float* out = (float*)d_out;

  float* hfW  = (float*)d_ws;            // [1024*784]
  float* x12W = hfW + BATCH * PP;        // [1024*64]

  convtda_kernel<<<2 * BATCH, 256, 0, stream>>>(
      x, conv_w1, conv_b1, conv_w2, conv_b2,
      dtm005, dtm02, g1_w, g1_b, g2_w, g2_b, hfW, x12W);
  fc_kernel<<<BATCH / 4, 256, 0, stream>>>(hfW, x12W, fc1_w, fc1_b, fc2_w, fc2_b, out);
}

// Round 3
// 128.509 us; speedup vs baseline: 1.3319x; 1.0125x over previous
//
#include <hip/hip_runtime.h>

#define BATCH 1024
#define PP 784          // 28*28

// ============= ONE fused kernel: conv + TDA + FC1 + FC2, one sample/block =============
// The whole net is per-sample independent, so block b computes sample b end-to-end:
//  phase 1: stage input tile + conv weights in LDS; issue TDA global loads into regs
//  phase 2: conv1->relu->conv2->relu, register-rolling, no h1 LDS array
//  phase 3: TDA (min1,min2,max) reduce + closed-form landscape @ g_w matmul
//  phase 4: FC1 (848x64) with 4-way i-split, FC2 (64x10)
__global__ __launch_bounds__(256) void fused_kernel(
    const float* __restrict__ xin,
    const float* __restrict__ dtm1, const float* __restrict__ dtm2,
    const float* __restrict__ w1g, const float* __restrict__ b1g,
    const float* __restrict__ w2g, const float* __restrict__ b2g,
    const float* __restrict__ g1w, const float* __restrict__ g1b,
    const float* __restrict__ g2w, const float* __restrict__ g2b,
    const float* __restrict__ fc1w, const float* __restrict__ fc1b,
    const float* __restrict__ fc2w, const float* __restrict__ fc2b,
    float* __restrict__ out)
{
  const int b = blockIdx.x;
  const int tid = threadIdx.x;
  const int lane = tid & 63;
  const int w = tid >> 6;          // wave id 0..3
  const int x = lane & 31;         // x position (28 valid)
  const int sub = lane >> 5;       // sub-channel 0/1

  __shared__ float inL[28][36];    // col0 & cols29..35 zero; col x+1 = image col x
  __shared__ float w1L[9][32];     // [tap][c]
  __shared__ float w2L[9][32];
  __shared__ float b1L[32];
  __shared__ float pL[4][28][28];  // per-wave partial conv2 sums
  __shared__ __align__(16) float zL[864];   // 784 conv + 64 tda (848 used)
  __shared__ float red[2][4][3];   // tda per-wave partials
  __shared__ float fin[2][3];
  __shared__ float pfc[4][64];     // fc1 partials per i-slice
  __shared__ float z1L[64];

  // ---- phase 0: issue TDA loads early (latency hides under conv) ----
  float4 tv1, tv2;
  if (tid < 196) {
    tv1 = *(const float4*)&dtm1[b * PP + tid * 4];
    tv2 = *(const float4*)&dtm2[b * PP + tid * 4];
  }

  // ---- phase 1: stage input tile + weights ----
  for (int i = tid; i < 224; i += 256) {
    int y = i >> 3, k = i & 7;
    inL[y][k == 0 ? 0 : 28 + k] = 0.f;
  }
  for (int i = tid; i < 784; i += 256)
    inL[i / 28][i % 28 + 1] = xin[b * PP + i];
  for (int i = tid; i < 288; i += 256) {
    ((float*)w1L)[i] = w1g[i];
    ((float*)w2L)[i] = w2g[i];
  }
  if (tid < 32) b1L[tid] = b1g[tid];
  __syncthreads();

  // ---- phase 2: conv (wave w owns channels 8w..8w+7; lane = x + 32*sub) ----
  float acc[28];
#pragma unroll
  for (int y = 0; y < 28; ++y) acc[y] = 0.f;

#pragma unroll 1
  for (int cp = 0; cp < 4; ++cp) {
    const int c = (w << 3) + (cp << 1) + sub;
    float wa[9], wb[9];
#pragma unroll
    for (int t = 0; t < 9; ++t) { wa[t] = w1L[t][c]; wb[t] = w2L[t][c]; }
    const float bb = b1L[c];

    float ra0 = 0.f, ra1 = 0.f, ra2 = 0.f;
    float rb0 = inL[0][x], rb1 = inL[0][x + 1], rb2 = inL[0][x + 2];

#pragma unroll
    for (int y = 0; y < 28; ++y) {
      float rc0, rc1, rc2;
      if (y + 1 < 28) {
        rc0 = inL[y + 1][x]; rc1 = inL[y + 1][x + 1]; rc2 = inL[y + 1][x + 2];
      } else {
        rc0 = 0.f; rc1 = 0.f; rc2 = 0.f;
      }
      float h = bb;
      h = fmaf(ra0, wa[0], h); h = fmaf(ra1, wa[1], h); h = fmaf(ra2, wa[2], h);
      h = fmaf(rb0, wa[3], h); h = fmaf(rb1, wa[4], h); h = fmaf(rb2, wa[5], h);
      h = fmaf(rc0, wa[6], h); h = fmaf(rc1, wa[7], h); h = fmaf(rc2, wa[8], h);
      h = (x < 28) ? fmaxf(h, 0.f) : 0.f;            // h1[y][x][c]
      float hl = __shfl_up(h, 1, 32);  hl = (x == 0) ? 0.f : hl;
      float hr = __shfl_down(h, 1, 32);
      if (y + 1 < 28) {
        acc[y + 1] = fmaf(hl, wb[0], acc[y + 1]);
        acc[y + 1] = fmaf(h , wb[1], acc[y + 1]);
        acc[y + 1] = fmaf(hr, wb[2], acc[y + 1]);
      }
      acc[y] = fmaf(hl, wb[3], acc[y]);
      acc[y] = fmaf(h , wb[4], acc[y]);
      acc[y] = fmaf(hr, wb[5], acc[y]);
      if (y > 0) {
        acc[y - 1] = fmaf(hl, wb[6], acc[y - 1]);
        acc[y - 1] = fmaf(h , wb[7], acc[y - 1]);
        acc[y - 1] = fmaf(hr, wb[8], acc[y - 1]);
      }
      ra0 = rb0; ra1 = rb1; ra2 = rb2;
      rb0 = rc0; rb1 = rc1; rb2 = rc2;
    }
  }
#pragma unroll
  for (int y = 0; y < 28; ++y) acc[y] += __shfl_xor(acc[y], 32);
  if (sub == 0 && x < 28) {
#pragma unroll
    for (int y = 0; y < 28; ++y) pL[w][y][x] = acc[y];
  }
  __syncthreads();

  // ---- phase 3a: conv epilogue -> zL[0..783]; TDA local+wave reduce ----
  {
    const float b2v = b2g[0];
    const float* pw = (const float*)pL;
    for (int u = tid; u < 784; u += 256) {
      float v = pw[u] + pw[784 + u] + pw[1568 + u] + pw[2352 + u] + b2v;
      zL[u] = fmaxf(v, 0.f);
    }
  }
#pragma unroll
  for (int br = 0; br < 2; ++br) {
    float m1 = 1e30f, m2 = 1e30f, mx = -1e30f;
    if (tid < 196) {
      float4 x4 = br ? tv2 : tv1;
      float xs[4] = {x4.x, x4.y, x4.z, x4.w};
#pragma unroll
      for (int k = 0; k < 4; ++k) {
        float v = xs[k];
        mx = fmaxf(mx, v);
        float nm1 = fminf(m1, v);
        m2 = fminf(m2, fmaxf(m1, v));
        m1 = nm1;
      }
    }
#pragma unroll
    for (int off = 32; off >= 1; off >>= 1) {
      float o1 = __shfl_xor(m1, off);
      float o2 = __shfl_xor(m2, off);
      float ox = __shfl_xor(mx, off);
      mx = fmaxf(mx, ox);
      float nm1 = fminf(m1, o1);
      m2 = fminf(fminf(m2, o2), fmaxf(m1, o1));
      m1 = nm1;
    }
    if ((tid & 63) == 0) {
      red[br][w][0] = m1; red[br][w][1] = m2; red[br][w][2] = mx;
    }
  }
  __syncthreads();
  if (tid < 2) {
    float m1 = 1e30f, m2 = 1e30f, mx = -1e30f;
#pragma unroll
    for (int wv = 0; wv < 4; ++wv) {
      float o1 = red[tid][wv][0], o2 = red[tid][wv][1], ox = red[tid][wv][2];
      mx = fmaxf(mx, ox);
      float nm1 = fminf(m1, o1);
      m2 = fminf(fminf(m2, o2), fmaxf(m1, o1));
      m1 = nm1;
    }
    fin[tid][0] = m1; fin[tid][1] = m2; fin[tid][2] = mx;
  }
  __syncthreads();
  // ---- phase 3b: landscape @ g_w -> zL[784..847] ----
  if (tid < 64) {
    const int br = tid >> 5, j = tid & 31;
    const float m1 = fin[br][0], m2 = fin[br][1], mx = fin[br][2];
    const float* gw = br ? g2w : g1w;
    const float* gb = br ? g2b : g1b;
    const float t0 = br ? 0.05f : 0.01f;
    const float dt = br ? (0.25f / 31.0f) : (0.28f / 31.0f);
    float a = gb[j];
#pragma unroll 4
    for (int i = 0; i < 64; ++i) {
      const int k = i >> 5, ti = i & 31;
      float tv = t0 + dt * (float)ti;
      float vk = k ? m2 : m1;
      float lam = fmaxf(0.0f, fminf(tv - vk, mx - tv));
      a = fmaf(lam, gw[i * 32 + j], a);
    }
    zL[784 + br * 32 + j] = fmaxf(a, 0.0f);
  }
  __syncthreads();

  // ---- phase 4: FC1 (j = tid&63, 4-way split over i) ----
  {
    const int j = tid & 63, part = tid >> 6;
    float a = 0.f;
    const int i0 = part * 212;
#pragma unroll 4
    for (int i = i0; i < i0 + 212; i += 4) {
      float4 z4 = *(float4*)&zL[i];
      a = fmaf(z4.x, fc1w[(i + 0) * 64 + j], a);
      a = fmaf(z4.y, fc1w[(i + 1) * 64 + j], a);
      a = fmaf(z4.z, fc1w[(i + 2) * 64 + j], a);
      a = fmaf(z4.w, fc1w[(i + 3) * 64 + j], a);
    }
    pfc[part][j] = a;
  }
  __syncthreads();
  if (tid < 64) {
    float v = pfc[0][tid] + pfc[1][tid] + pfc[2][tid] + pfc[3][tid] + fc1b[tid];
    z1L[tid] = fmaxf(v, 0.f);
  }
  __syncthreads();
  // ---- FC2 ----
  if (tid < 10) {
    float a = fc2b[tid];
#pragma unroll 8
    for (int jj = 0; jj < 64; ++jj)
      a = fmaf(z1L[jj], fc2w[jj * 10 + tid], a);
    out[b * 10 + tid] = a;
  }
}

extern "C" void kernel_launch(void* const* d_in, const int* in_sizes, int n_in,
                              void* d_out, int out_size, void* d_ws, size_t ws_size,
                              hipStream_t stream) {
  const float* x       = (const float*)d_in[0];
  const float* dtm005  = (const float*)d_in[1];
  const float* dtm02   = (const float*)d_in[2];
  const float* conv_w1 = (const float*)d_in[3];
  const float* conv_b1 = (const float*)d_in[4];
  const float* conv_w2 = (const float*)d_in[5];
  const float* conv_b2 = (const float*)d_in[6];
  const float* g1_w    = (const float*)d_in[7];
  const float* g1_b    = (const float*)d_in[8];
  const float* g2_w    = (const float*)d_in[9];
  const float* g2_b    = (const float*)d_in[10];
  const float* fc1_w   = (const float*)d_in[11];
  const float* fc1_b   = (const float*)d_in[12];
  const float* fc2_w   = (const float*)d_in[13];
  const float* fc2_b   = (const float*)d_in[14];
  float* out = (float*)d_out;

  fused_kernel<<<BATCH, 256, 0, stream>>>(
      x, dtm005, dtm02, conv_w1, conv_b1, conv_w2, conv_b2,
      g1_w, g1_b, g2_w, g2_b, fc1_w, fc1_b, fc2_w, fc2_b, out);
}